// Round 3
// baseline (595.345 us; speedup 1.0000x reference)
//
#include <hip/hip_runtime.h>
#include <stdint.h>

#define SEQ_LEN 3120
#define DIM 1536
#define QKV_N 4608
#define HEADS 12
#define HEAD_DIM 128
#define FRAME_LEN 1560
#define SM_SCALE 0.08838834764831845f // 1/sqrt(128)

typedef short short8 __attribute__((ext_vector_type(8)));
typedef float f32x4 __attribute__((ext_vector_type(4)));
typedef float f32x16 __attribute__((ext_vector_type(16)));

// fp32 -> bf16 round-to-nearest-even (data has no NaN)
__device__ __forceinline__ unsigned short f2bf(float x) {
    union { float f; unsigned u; } v; v.f = x;
    unsigned r = v.u + 0x7fffu + ((v.u >> 16) & 1u);
    return (unsigned short)(r >> 16);
}

// async global->LDS, 16B per lane. lds base wave-uniform; dest = lds + lane*16.
__device__ __forceinline__ void async16(void* lds, const void* g) {
    __builtin_amdgcn_global_load_lds(
        (const __attribute__((address_space(1))) unsigned int*)g,
        (__attribute__((address_space(3))) unsigned int*)lds, 16, 0, 0);
}

// ---------------------------------------------------------------------------
// fp32 -> bf16 straight convert (8 elems/thread, exact grid)
// ---------------------------------------------------------------------------
__global__ __launch_bounds__(256) void convert_bf16_kernel(
    const float* __restrict__ in, unsigned short* __restrict__ out)
{
    const int i = blockIdx.x * 256 + threadIdx.x;
    const float4 a = ((const float4*)in)[i * 2];
    const float4 b = ((const float4*)in)[i * 2 + 1];
    union { unsigned short t[8]; uint4 u; } p;
    p.t[0] = f2bf(a.x); p.t[1] = f2bf(a.y); p.t[2] = f2bf(a.z); p.t[3] = f2bf(a.w);
    p.t[4] = f2bf(b.x); p.t[5] = f2bf(b.y); p.t[6] = f2bf(b.z); p.t[7] = f2bf(b.w);
    ((uint4*)out)[i] = p.u;
}

// ---------------------------------------------------------------------------
// fp32 [R][C] -> bf16 [C][R] tiled transpose-convert (64x64 tiles; R,C %64==0)
// ---------------------------------------------------------------------------
__global__ __launch_bounds__(256) void transpose_bf16_kernel(
    const float* __restrict__ in, unsigned short* __restrict__ out, int R, int C)
{
    __shared__ float T[64][65];
    const int tid = threadIdx.x;
    const int c0 = blockIdx.x * 64, r0 = blockIdx.y * 64;
    const int rl = tid >> 4, cl = (tid & 15) * 4;
#pragma unroll
    for (int i = 0; i < 4; ++i) {
        const int row = r0 + rl + i * 16;
        float4 v = *(const float4*)&in[(size_t)row * C + c0 + cl];
        T[cl + 0][rl + i * 16] = v.x; T[cl + 1][rl + i * 16] = v.y;
        T[cl + 2][rl + i * 16] = v.z; T[cl + 3][rl + i * 16] = v.w;
    }
    __syncthreads();
    const int oc = tid >> 2, ob = (tid & 3) * 16;
    union { unsigned short t[16]; uint4 u[2]; } p;
#pragma unroll
    for (int j = 0; j < 16; ++j) p.t[j] = f2bf(T[oc][ob + j]);
    uint4* dst = (uint4*)&out[(size_t)(c0 + oc) * R + r0 + ob];
    dst[0] = p.u[0];
    dst[1] = p.u[1];
}

// ---------------------------------------------------------------------------
// bf16 MFMA GEMM (m97 structure): C[M,N] = A[M,K] @ Bt[N,K]^T + bias, C fp32.
// 128x128 tile, BK=32, 256 thr = 4 waves (2x2 of 64x64), global_load_lds x16.
// ---------------------------------------------------------------------------
__global__ __launch_bounds__(256, 2) void gemm_bt_kernel(
    const unsigned short* __restrict__ A, const unsigned short* __restrict__ Bt,
    const float* __restrict__ bias, float* __restrict__ C, int M, int N, int K)
{
    __shared__ short As[128 * 32];
    __shared__ short Bs[128 * 32];

    const int tid = threadIdx.x;
    const int w = tid >> 6, l = tid & 63;
    const int m0 = blockIdx.y * 128, n0 = blockIdx.x * 128;
    const int wr = w >> 1, wc = w & 1;
    const int lhi = l >> 4, llo = l & 15;

    f32x4 acc[4][4];
#pragma unroll
    for (int i = 0; i < 4; ++i)
#pragma unroll
        for (int j = 0; j < 4; ++j) acc[i][j] = f32x4{0.f, 0.f, 0.f, 0.f};

    const int c0i = (w * 2) * 64 + l, c1i = c0i + 64;
    const unsigned short* gA0 = A + (size_t)min(m0 + (c0i >> 2), M - 1) * K + (c0i & 3) * 8;
    const unsigned short* gA1 = A + (size_t)min(m0 + (c1i >> 2), M - 1) * K + (c1i & 3) * 8;
    const unsigned short* gB0 = Bt + (size_t)(n0 + (c0i >> 2)) * K + (c0i & 3) * 8;
    const unsigned short* gB1 = Bt + (size_t)(n0 + (c1i >> 2)) * K + (c1i & 3) * 8;
    short* lA0 = As + (w * 2 + 0) * 512;
    short* lA1 = As + (w * 2 + 1) * 512;
    short* lB0 = Bs + (w * 2 + 0) * 512;
    short* lB1 = Bs + (w * 2 + 1) * 512;

    const int aoff = (wr * 64 + llo) * 32 + lhi * 8;
    const int boff = (wc * 64 + llo) * 32 + lhi * 8;

    for (int k0 = 0; k0 < K; k0 += 32) {
        async16(lA0, gA0 + k0); async16(lA1, gA1 + k0);
        async16(lB0, gB0 + k0); async16(lB1, gB1 + k0);
        __syncthreads();
        short8 af[4], bf[4];
#pragma unroll
        for (int mt = 0; mt < 4; ++mt) af[mt] = *(const short8*)&As[aoff + mt * 512];
#pragma unroll
        for (int nt = 0; nt < 4; ++nt) bf[nt] = *(const short8*)&Bs[boff + nt * 512];
#pragma unroll
        for (int mt = 0; mt < 4; ++mt)
#pragma unroll
            for (int nt = 0; nt < 4; ++nt)
                acc[mt][nt] = __builtin_amdgcn_mfma_f32_16x16x32_bf16(af[mt], bf[nt], acc[mt][nt], 0, 0, 0);
        __syncthreads();
    }

#pragma unroll
    for (int mt = 0; mt < 4; ++mt)
#pragma unroll
        for (int ri = 0; ri < 4; ++ri) {
            const int row = m0 + wr * 64 + mt * 16 + lhi * 4 + ri;
            if (row < M) {
#pragma unroll
                for (int nt = 0; nt < 4; ++nt) {
                    const int col = n0 + wc * 64 + nt * 16 + llo;
                    C[(size_t)row * N + col] = acc[mt][nt][ri] + bias[col];
                }
            }
        }
}

// ---------------------------------------------------------------------------
// RMSNorm(q,k over DIM) + RoPE + bf16 quantize; q pre-scaled by 1/sqrt(hd).
// ---------------------------------------------------------------------------
__global__ __launch_bounds__(256) void rmsrope_kernel(
    const float* __restrict__ qkv, const float* __restrict__ gq,
    const float* __restrict__ gk, const float* __restrict__ cosf,
    const float* __restrict__ sinf, unsigned short* __restrict__ qb,
    unsigned short* __restrict__ kb)
{
    const int s = blockIdx.x;
    const int tid = threadIdx.x;
    const float* qrow = qkv + (size_t)s * QKV_N;
    const float* krow = qrow + DIM;

    float2 qp[3], kp[3];
    float ssq_q = 0.f, ssq_k = 0.f;
#pragma unroll
    for (int j = 0; j < 3; ++j) {
        const int p = tid + j * 256;
        qp[j] = *(const float2*)(qrow + 2 * p);
        kp[j] = *(const float2*)(krow + 2 * p);
        ssq_q += qp[j].x * qp[j].x + qp[j].y * qp[j].y;
        ssq_k += kp[j].x * kp[j].x + kp[j].y * kp[j].y;
    }
#pragma unroll
    for (int off = 32; off > 0; off >>= 1) {
        ssq_q += __shfl_down(ssq_q, off);
        ssq_k += __shfl_down(ssq_k, off);
    }
    __shared__ float wq[4], wk[4];
    const int wave = tid >> 6, lane = tid & 63;
    if (lane == 0) { wq[wave] = ssq_q; wk[wave] = ssq_k; }
    __syncthreads();
    const float tq = wq[0] + wq[1] + wq[2] + wq[3];
    const float tk = wk[0] + wk[1] + wk[2] + wk[3];
    const float inv_q = rsqrtf(tq * (1.0f / DIM) + 1e-6f) * SM_SCALE;
    const float inv_k = rsqrtf(tk * (1.0f / DIM) + 1e-6f);

#pragma unroll
    for (int j = 0; j < 3; ++j) {
        const int p = tid + j * 256;
        const int fi = p & 63;
        const float c = cosf[s * 64 + fi];
        const float si = sinf[s * 64 + fi];
        {
            const float y1 = qp[j].x * inv_q * gq[2 * p];
            const float y2 = qp[j].y * inv_q * gq[2 * p + 1];
            union { unsigned short t[2]; unsigned u; } o;
            o.t[0] = f2bf(y1 * c - y2 * si);
            o.t[1] = f2bf(y1 * si + y2 * c);
            *(unsigned*)&qb[(size_t)s * DIM + 2 * p] = o.u;
        }
        {
            const float y1 = kp[j].x * inv_k * gk[2 * p];
            const float y2 = kp[j].y * inv_k * gk[2 * p + 1];
            union { unsigned short t[2]; unsigned u; } o;
            o.t[0] = f2bf(y1 * c - y2 * si);
            o.t[1] = f2bf(y1 * si + y2 * c);
            *(unsigned*)&kb[(size_t)s * DIM + 2 * p] = o.u;
        }
    }
}

// ---------------------------------------------------------------------------
// V transpose: qkv v-part fp32 [s][h*128+d] -> vt bf16 [h][d][s]
// ---------------------------------------------------------------------------
__global__ __launch_bounds__(256) void vtrans_kernel(
    const float* __restrict__ qkv, unsigned short* __restrict__ vt)
{
    __shared__ float T[128][65];
    const int s0 = blockIdx.x * 64;
    const int h = blockIdx.y;
    const int tid = threadIdx.x;
    const int rl = tid >> 2, cb = (tid & 3) * 32;
    const int row = min(s0 + rl, SEQ_LEN - 1);
#pragma unroll
    for (int i = 0; i < 8; ++i) {
        const int d = cb + i * 4;
        float4 v = *(const float4*)&qkv[(size_t)row * QKV_N + 2 * DIM + h * HEAD_DIM + d];
        T[d + 0][rl] = v.x; T[d + 1][rl] = v.y; T[d + 2][rl] = v.z; T[d + 3][rl] = v.w;
    }
    __syncthreads();
    const int od = tid >> 1, ob = (tid & 1) * 32;
    const size_t orow = (size_t)(h * HEAD_DIM + od) * SEQ_LEN;
#pragma unroll
    for (int v8 = 0; v8 < 4; ++v8) {
        const int s = s0 + ob + v8 * 8;
        if (s < SEQ_LEN) { // SEQ_LEN % 8 == 0, so vector never straddles
            union { unsigned short t[8]; uint4 u; } pk;
#pragma unroll
            for (int j = 0; j < 8; ++j) pk.t[j] = f2bf(T[od][ob + v8 * 8 + j]);
            *(uint4*)&vt[orow + s] = pk.u;
        }
    }
}

// ---------------------------------------------------------------------------
// Flash attention via 32x32x16 bf16 MFMA, transposed-score formulation.
// Block = 128 thr (2 waves), BQ=64 (32 q/wave), BK=64.
// S^T = K Q^T  (A=K from swizzled LDS, B=Q in regs)  -> per-lane q = lane&31
// O^T += V^T P^T (A=V^T from swizzled LDS, B=P^T via half-wave reg exchange)
// ---------------------------------------------------------------------------
__global__ __launch_bounds__(128) void attn_mfma2_kernel(
    const unsigned short* __restrict__ qb, const unsigned short* __restrict__ kb,
    const unsigned short* __restrict__ vt, unsigned short* __restrict__ attb)
{
    __shared__ short Ks[64 * 128]; // 16KB, xor-swizzled [key][dgrp^(key&7)]
    __shared__ short Vs[128 * 64]; // 16KB, xor-swizzled [d][kgrp^(d&7)]

    const int tid = threadIdx.x;
    const int wv = tid >> 6;
    const int l  = tid & 63;
    const int h  = blockIdx.y;
    const int q0 = blockIdx.x * 64;
    const int lhi = l >> 5;   // half-wave id
    const int llo = l & 31;

    // ---- one-time: stage Q linear into Ks, pull B-frags to registers ----
#pragma unroll
    for (int s = 0; s < 8; ++s) {
        const int shot = wv * 8 + s;
        const int row = shot * 4 + (l >> 4);
        const int gq = l & 15;
        const int gr = min(q0 + row, SEQ_LEN - 1);
        async16(Ks + shot * 512, qb + (size_t)gr * DIM + h * HEAD_DIM + gq * 8);
    }
    __syncthreads();
    short8 qf[8];
#pragma unroll
    for (int ds = 0; ds < 8; ++ds)
        qf[ds] = *(const short8*)&Ks[(wv * 32 + llo) * 128 + ds * 16 + lhi * 8];
    __syncthreads();

    const int myq = q0 + wv * 32 + llo;
    const int mylimit = (myq < FRAME_LEN) ? FRAME_LEN : SEQ_LEN;
    const int wave_lim = (q0 + wv * 32 < FRAME_LEN) ? FRAME_LEN : SEQ_LEN;
    const int Lmax = (q0 + 63 >= FRAME_LEN) ? SEQ_LEN : FRAME_LEN;

    float m_run = -3.0e38f, l_run = 0.f;
    f32x16 o[4];
#pragma unroll
    for (int mt = 0; mt < 4; ++mt)
#pragma unroll
        for (int r = 0; r < 16; ++r) o[mt][r] = 0.f;

    // per-lane staging descriptors (loop-invariant)
    int ksr[8], kco[8], vco[8];
    size_t vrow[8];
#pragma unroll
    for (int s = 0; s < 8; ++s) {
        const int shot = wv * 8 + s;
        const int krow = shot * 4 + (l >> 4);
        ksr[s] = krow;
        kco[s] = h * HEAD_DIM + ((l & 15) ^ (krow & 7)) * 8;
        const int d = shot * 8 + (l >> 3);
        vrow[s] = (size_t)(h * HEAD_DIM + d) * SEQ_LEN;
        vco[s] = ((l & 7) ^ (d & 7)) * 8;
    }

    for (int kc = 0; kc < Lmax; kc += 64) {
        // ---- stage K (row-clamped) and V^T (col-clamped), xor-swizzled ----
#pragma unroll
        for (int s = 0; s < 8; ++s) {
            const int gr = min(kc + ksr[s], SEQ_LEN - 1);
            async16(Ks + (wv * 8 + s) * 512, kb + (size_t)gr * DIM + kco[s]);
        }
#pragma unroll
        for (int s = 0; s < 8; ++s) {
            const int col = min(kc + vco[s], SEQ_LEN - 8);
            async16(Vs + (wv * 8 + s) * 512, vt + vrow[s] + col);
        }
        __syncthreads();

        // ---- S^T = K Q^T : two 32x32 tiles per wave ----
        f32x16 st[2];
#pragma unroll
        for (int r = 0; r < 16; ++r) { st[0][r] = 0.f; st[1][r] = 0.f; }
#pragma unroll
        for (int ds = 0; ds < 8; ++ds) {
            const int gd = ds * 2 + lhi;
#pragma unroll
            for (int kt = 0; kt < 2; ++kt) {
                const int krow = kt * 32 + llo;
                short8 kf = *(const short8*)&Ks[krow * 128 + ((gd ^ (krow & 7)) * 8)];
                st[kt] = __builtin_amdgcn_mfma_f32_32x32x16_bf16(kf, qf[ds], st[kt], 0, 0, 0);
            }
        }

        // ---- block-causal / tail mask ----
        if (kc + 64 > wave_lim) {
#pragma unroll
            for (int kt = 0; kt < 2; ++kt)
#pragma unroll
                for (int r = 0; r < 16; ++r) {
                    const int kg = kc + kt * 32 + (r & 3) + 8 * (r >> 2) + 4 * lhi;
                    if (kg >= mylimit) st[kt][r] = -3.0e38f;
                }
        }

        // ---- online softmax: per-lane scalar state, partner = lane^32 ----
        float vmax = st[0][0];
#pragma unroll
        for (int r = 1; r < 16; ++r) vmax = fmaxf(vmax, st[0][r]);
#pragma unroll
        for (int r = 0; r < 16; ++r) vmax = fmaxf(vmax, st[1][r]);
        vmax = fmaxf(vmax, __shfl_xor(vmax, 32));
        const float mn = fmaxf(m_run, vmax);
        const float alpha = __expf(m_run - mn);
        m_run = mn;
        float rs = 0.f;
        unsigned p16[2][8]; // P^T as bf16 pairs (dword d holds regs 2d,2d+1)
#pragma unroll
        for (int kt = 0; kt < 2; ++kt)
#pragma unroll
            for (int r2 = 0; r2 < 8; ++r2) {
                const float p0 = __expf(st[kt][2 * r2] - mn);
                const float p1 = __expf(st[kt][2 * r2 + 1] - mn);
                rs += p0 + p1;
                p16[kt][r2] = (unsigned)f2bf(p0) | ((unsigned)f2bf(p1) << 16);
            }
        rs += __shfl_xor(rs, 32);
        l_run = l_run * alpha + rs;
#pragma unroll
        for (int mt = 0; mt < 4; ++mt)
#pragma unroll
            for (int r = 0; r < 16; ++r) o[mt][r] *= alpha;

        // ---- O^T += V^T P^T : P^T B-frags via half-wave exchange ----
#pragma unroll
        for (int kblk = 0; kblk < 4; ++kblk) {
            const int t = kblk >> 1;
            const int dk    = ((kblk & 1) * 2 + lhi) * 2;       // keep dwords
            const int dsend = ((kblk & 1) * 2 + (1 - lhi)) * 2; // export dwords
            const unsigned r0 = __shfl_xor(p16[t][dsend], 32);
            const unsigned r1 = __shfl_xor(p16[t][dsend + 1], 32);
            union { unsigned u[4]; short8 s8; } pf;
            if (lhi == 0) { pf.u[0] = p16[t][dk]; pf.u[1] = p16[t][dk + 1]; pf.u[2] = r0; pf.u[3] = r1; }
            else          { pf.u[0] = r0; pf.u[1] = r1; pf.u[2] = p16[t][dk]; pf.u[3] = p16[t][dk + 1]; }
            const int gk = kblk * 2 + lhi;
#pragma unroll
            for (int mt = 0; mt < 4; ++mt) {
                const int vd = mt * 32 + llo;
                short8 vf = *(const short8*)&Vs[vd * 64 + ((gk ^ (vd & 7)) * 8)];
                o[mt] = __builtin_amdgcn_mfma_f32_32x32x16_bf16(vf, pf.s8, o[mt], 0, 0, 0);
            }
        }
        __syncthreads();
    }

    // ---- epilogue: O^T regs -> attb[s][h*128+d], packed 4-bf16 stores ----
    if (myq < SEQ_LEN) {
        const float inv = 1.0f / l_run;
        unsigned short* op = attb + (size_t)myq * DIM + h * HEAD_DIM + 4 * lhi;
#pragma unroll
        for (int mt = 0; mt < 4; ++mt)
#pragma unroll
            for (int g = 0; g < 4; ++g) {
                union { unsigned short t4[4]; uint2 u; } pk;
#pragma unroll
                for (int i = 0; i < 4; ++i) pk.t4[i] = f2bf(o[mt][4 * g + i] * inv);
                *(uint2*)&op[mt * 32 + 8 * g] = pk.u;
            }
    }
}

// ---------------------------------------------------------------------------
extern "C" void kernel_launch(void* const* d_in, const int* in_sizes, int n_in,
                              void* d_out, int out_size, void* d_ws, size_t ws_size,
                              hipStream_t stream)
{
    const float* hs    = (const float*)d_in[0];
    const float* cosf  = (const float*)d_in[1];
    const float* sinf  = (const float*)d_in[2];
    const float* w_qkv = (const float*)d_in[3];
    const float* b_qkv = (const float*)d_in[4];
    const float* g_q   = (const float*)d_in[5];
    const float* g_k   = (const float*)d_in[6];
    const float* w_out = (const float*)d_in[7];
    const float* b_out = (const float*)d_in[8];

    // workspace layout, 105,136,128 B total. Order chosen so the attention
    // kernel's bounded overreads (K: +16 rows past kb; V: +16 B past vt)
    // land in allocated, finite-valued regions.
    char* base = (char*)d_ws;
    unsigned short* qb    = (unsigned short*)base;                 //  9,584,640
    unsigned short* kb    = (unsigned short*)(base + 9584640);     //  9,584,640
    unsigned short* vt    = (unsigned short*)(base + 19169280);    //  9,584,640 (alias hsb)
    unsigned short* hsb   = vt;
    float*          qkv   = (float*)(base + 28753920);             // 57,507,840
    unsigned short* wqkvT = (unsigned short*)(base + 86261760);    // 14,155,776 (alias attb)
    unsigned short* attb  = wqkvT;
    unsigned short* woutT = (unsigned short*)(base + 100417536);   //  4,718,592
    float* outp = (float*)d_out;

    // 1) hs -> bf16
    convert_bf16_kernel<<<2340, 256, 0, stream>>>(hs, hsb);
    // 2) w_qkv -> bf16 transposed [4608][1536]
    transpose_bf16_kernel<<<dim3(QKV_N / 64, DIM / 64), 256, 0, stream>>>(w_qkv, wqkvT, DIM, QKV_N);
    // 3) w_out -> bf16 transposed [1536][1536]
    transpose_bf16_kernel<<<dim3(DIM / 64, DIM / 64), 256, 0, stream>>>(w_out, woutT, DIM, DIM);
    // 4) qkv = hs @ w_qkv + b_qkv (fp32 out)
    gemm_bt_kernel<<<dim3(QKV_N / 128, (SEQ_LEN + 127) / 128), 256, 0, stream>>>(
        hsb, wqkvT, b_qkv, qkv, SEQ_LEN, QKV_N, DIM);
    // 5) rmsnorm+rope -> qb, kb (q pre-scaled by 1/sqrt(hd))
    rmsrope_kernel<<<SEQ_LEN, 256, 0, stream>>>(qkv, g_q, g_k, cosf, sinf, qb, kb);
    // 6) v -> vt bf16 [h][d][s]
    vtrans_kernel<<<dim3((SEQ_LEN + 63) / 64, HEADS), 256, 0, stream>>>(qkv, vt);
    // 7) attention -> attb bf16 [s][h*128+d]
    attn_mfma2_kernel<<<dim3((SEQ_LEN + 63) / 64, HEADS), 128, 0, stream>>>(qb, kb, vt, attb);
    // 8) out = attb @ w_out + b_out (fp32)
    gemm_bt_kernel<<<dim3(DIM / 128, (SEQ_LEN + 127) / 128), 256, 0, stream>>>(
        attb, woutT, b_out, outp, SEQ_LEN, DIM, DIM);
}

// Round 4
// 438.370 us; speedup vs baseline: 1.3581x; 1.3581x over previous
//
#include <hip/hip_runtime.h>
#include <stdint.h>

#define SEQ_LEN 3120
#define DIM 1536
#define QKV_N 4608
#define HEADS 12
#define HEAD_DIM 128
#define FRAME_LEN 1560
#define SM_SCALE 0.08838834764831845f // 1/sqrt(128)
#define NSPLIT 4
#define BQ 128

typedef short short8 __attribute__((ext_vector_type(8)));
typedef float f32x4 __attribute__((ext_vector_type(4)));
typedef float f32x16 __attribute__((ext_vector_type(16)));

// fp32 -> bf16 round-to-nearest-even (data has no NaN)
__device__ __forceinline__ unsigned short f2bf(float x) {
    union { float f; unsigned u; } v; v.f = x;
    unsigned r = v.u + 0x7fffu + ((v.u >> 16) & 1u);
    return (unsigned short)(r >> 16);
}
__device__ __forceinline__ float bf2f(unsigned short b) {
    union { unsigned u; float f; } v; v.u = ((unsigned)b) << 16;
    return v.f;
}

// async global->LDS, 16B per lane. lds base wave-uniform; dest = lds + lane*16.
__device__ __forceinline__ void async16(void* lds, const void* g) {
    __builtin_amdgcn_global_load_lds(
        (const __attribute__((address_space(1))) unsigned int*)g,
        (__attribute__((address_space(3))) unsigned int*)lds, 16, 0, 0);
}

// ---------------------------------------------------------------------------
// fp32 -> bf16 straight convert
// ---------------------------------------------------------------------------
__global__ __launch_bounds__(256) void convert_bf16_kernel(
    const float* __restrict__ in, unsigned short* __restrict__ out)
{
    const int i = blockIdx.x * 256 + threadIdx.x;
    const float4 a = ((const float4*)in)[i * 2];
    const float4 b = ((const float4*)in)[i * 2 + 1];
    union { unsigned short t[8]; uint4 u; } p;
    p.t[0] = f2bf(a.x); p.t[1] = f2bf(a.y); p.t[2] = f2bf(a.z); p.t[3] = f2bf(a.w);
    p.t[4] = f2bf(b.x); p.t[5] = f2bf(b.y); p.t[6] = f2bf(b.z); p.t[7] = f2bf(b.w);
    ((uint4*)out)[i] = p.u;
}

// ---------------------------------------------------------------------------
// fp32 [R][C] -> bf16 [C][R] tiled transpose-convert (R,C % 64 == 0)
// ---------------------------------------------------------------------------
__global__ __launch_bounds__(256) void transpose_bf16_kernel(
    const float* __restrict__ in, unsigned short* __restrict__ out, int R, int C)
{
    __shared__ float T[64][65];
    const int tid = threadIdx.x;
    const int c0 = blockIdx.x * 64, r0 = blockIdx.y * 64;
    const int rl = tid >> 4, cl = (tid & 15) * 4;
#pragma unroll
    for (int i = 0; i < 4; ++i) {
        const int row = r0 + rl + i * 16;
        float4 v = *(const float4*)&in[(size_t)row * C + c0 + cl];
        T[cl + 0][rl + i * 16] = v.x; T[cl + 1][rl + i * 16] = v.y;
        T[cl + 2][rl + i * 16] = v.z; T[cl + 3][rl + i * 16] = v.w;
    }
    __syncthreads();
    const int oc = tid >> 2, ob = (tid & 3) * 16;
    union { unsigned short t[16]; uint4 u[2]; } p;
#pragma unroll
    for (int j = 0; j < 16; ++j) p.t[j] = f2bf(T[oc][ob + j]);
    uint4* dst = (uint4*)&out[(size_t)(c0 + oc) * R + r0 + ob];
    dst[0] = p.u[0];
    dst[1] = p.u[1];
}

// ---------------------------------------------------------------------------
// bf16 MFMA GEMM: C[M,N] = A[M,K] @ Bt[N,K]^T + bias, C fp32. (m97 structure)
// ---------------------------------------------------------------------------
__global__ __launch_bounds__(256, 2) void gemm_bt_kernel(
    const unsigned short* __restrict__ A, const unsigned short* __restrict__ Bt,
    const float* __restrict__ bias, float* __restrict__ C, int M, int N, int K)
{
    __shared__ short As[128 * 32];
    __shared__ short Bs[128 * 32];

    const int tid = threadIdx.x;
    const int w = tid >> 6, l = tid & 63;
    const int m0 = blockIdx.y * 128, n0 = blockIdx.x * 128;
    const int wr = w >> 1, wc = w & 1;
    const int lhi = l >> 4, llo = l & 15;

    f32x4 acc[4][4];
#pragma unroll
    for (int i = 0; i < 4; ++i)
#pragma unroll
        for (int j = 0; j < 4; ++j) acc[i][j] = f32x4{0.f, 0.f, 0.f, 0.f};

    const int c0i = (w * 2) * 64 + l, c1i = c0i + 64;
    const unsigned short* gA0 = A + (size_t)min(m0 + (c0i >> 2), M - 1) * K + (c0i & 3) * 8;
    const unsigned short* gA1 = A + (size_t)min(m0 + (c1i >> 2), M - 1) * K + (c1i & 3) * 8;
    const unsigned short* gB0 = Bt + (size_t)(n0 + (c0i >> 2)) * K + (c0i & 3) * 8;
    const unsigned short* gB1 = Bt + (size_t)(n0 + (c1i >> 2)) * K + (c1i & 3) * 8;
    short* lA0 = As + (w * 2 + 0) * 512;
    short* lA1 = As + (w * 2 + 1) * 512;
    short* lB0 = Bs + (w * 2 + 0) * 512;
    short* lB1 = Bs + (w * 2 + 1) * 512;

    const int aoff = (wr * 64 + llo) * 32 + lhi * 8;
    const int boff = (wc * 64 + llo) * 32 + lhi * 8;

    for (int k0 = 0; k0 < K; k0 += 32) {
        async16(lA0, gA0 + k0); async16(lA1, gA1 + k0);
        async16(lB0, gB0 + k0); async16(lB1, gB1 + k0);
        __syncthreads();
        short8 af[4], bf[4];
#pragma unroll
        for (int mt = 0; mt < 4; ++mt) af[mt] = *(const short8*)&As[aoff + mt * 512];
#pragma unroll
        for (int nt = 0; nt < 4; ++nt) bf[nt] = *(const short8*)&Bs[boff + nt * 512];
#pragma unroll
        for (int mt = 0; mt < 4; ++mt)
#pragma unroll
            for (int nt = 0; nt < 4; ++nt)
                acc[mt][nt] = __builtin_amdgcn_mfma_f32_16x16x32_bf16(af[mt], bf[nt], acc[mt][nt], 0, 0, 0);
        __syncthreads();
    }

#pragma unroll
    for (int mt = 0; mt < 4; ++mt)
#pragma unroll
        for (int ri = 0; ri < 4; ++ri) {
            const int row = m0 + wr * 64 + mt * 16 + lhi * 4 + ri;
            if (row < M) {
#pragma unroll
                for (int nt = 0; nt < 4; ++nt) {
                    const int col = n0 + wc * 64 + nt * 16 + llo;
                    C[(size_t)row * N + col] = acc[mt][nt][ri] + bias[col];
                }
            }
        }
}

// ---------------------------------------------------------------------------
// RMSNorm(q,k over DIM) + RoPE + bf16 quantize; q pre-scaled by 1/sqrt(hd).
// ---------------------------------------------------------------------------
__global__ __launch_bounds__(256) void rmsrope_kernel(
    const float* __restrict__ qkv, const float* __restrict__ gq,
    const float* __restrict__ gk, const float* __restrict__ cosf,
    const float* __restrict__ sinf, unsigned short* __restrict__ qb,
    unsigned short* __restrict__ kb)
{
    const int s = blockIdx.x;
    const int tid = threadIdx.x;
    const float* qrow = qkv + (size_t)s * QKV_N;
    const float* krow = qrow + DIM;

    float2 qp[3], kp[3];
    float ssq_q = 0.f, ssq_k = 0.f;
#pragma unroll
    for (int j = 0; j < 3; ++j) {
        const int p = tid + j * 256;
        qp[j] = *(const float2*)(qrow + 2 * p);
        kp[j] = *(const float2*)(krow + 2 * p);
        ssq_q += qp[j].x * qp[j].x + qp[j].y * qp[j].y;
        ssq_k += kp[j].x * kp[j].x + kp[j].y * kp[j].y;
    }
#pragma unroll
    for (int off = 32; off > 0; off >>= 1) {
        ssq_q += __shfl_down(ssq_q, off);
        ssq_k += __shfl_down(ssq_k, off);
    }
    __shared__ float wq[4], wk[4];
    const int wave = tid >> 6, lane = tid & 63;
    if (lane == 0) { wq[wave] = ssq_q; wk[wave] = ssq_k; }
    __syncthreads();
    const float tq = wq[0] + wq[1] + wq[2] + wq[3];
    const float tk = wk[0] + wk[1] + wk[2] + wk[3];
    const float inv_q = rsqrtf(tq * (1.0f / DIM) + 1e-6f) * SM_SCALE;
    const float inv_k = rsqrtf(tk * (1.0f / DIM) + 1e-6f);

#pragma unroll
    for (int j = 0; j < 3; ++j) {
        const int p = tid + j * 256;
        const int fi = p & 63;
        const float c = cosf[s * 64 + fi];
        const float si = sinf[s * 64 + fi];
        {
            const float y1 = qp[j].x * inv_q * gq[2 * p];
            const float y2 = qp[j].y * inv_q * gq[2 * p + 1];
            union { unsigned short t[2]; unsigned u; } o;
            o.t[0] = f2bf(y1 * c - y2 * si);
            o.t[1] = f2bf(y1 * si + y2 * c);
            *(unsigned*)&qb[(size_t)s * DIM + 2 * p] = o.u;
        }
        {
            const float y1 = kp[j].x * inv_k * gk[2 * p];
            const float y2 = kp[j].y * inv_k * gk[2 * p + 1];
            union { unsigned short t[2]; unsigned u; } o;
            o.t[0] = f2bf(y1 * c - y2 * si);
            o.t[1] = f2bf(y1 * si + y2 * c);
            *(unsigned*)&kb[(size_t)s * DIM + 2 * p] = o.u;
        }
    }
}

// ---------------------------------------------------------------------------
// V transpose: qkv v-part fp32 [s][h*128+d] -> vt bf16 [h][d][s]
// ---------------------------------------------------------------------------
__global__ __launch_bounds__(256) void vtrans_kernel(
    const float* __restrict__ qkv, unsigned short* __restrict__ vt)
{
    __shared__ float T[128][65];
    const int s0 = blockIdx.x * 64;
    const int h = blockIdx.y;
    const int tid = threadIdx.x;
    const int rl = tid >> 2, cb = (tid & 3) * 32;
    const int row = min(s0 + rl, SEQ_LEN - 1);
#pragma unroll
    for (int i = 0; i < 8; ++i) {
        const int d = cb + i * 4;
        float4 v = *(const float4*)&qkv[(size_t)row * QKV_N + 2 * DIM + h * HEAD_DIM + d];
        T[d + 0][rl] = v.x; T[d + 1][rl] = v.y; T[d + 2][rl] = v.z; T[d + 3][rl] = v.w;
    }
    __syncthreads();
    const int od = tid >> 1, ob = (tid & 1) * 32;
    const size_t orow = (size_t)(h * HEAD_DIM + od) * SEQ_LEN;
#pragma unroll
    for (int v8 = 0; v8 < 4; ++v8) {
        const int s = s0 + ob + v8 * 8;
        if (s < SEQ_LEN) {
            union { unsigned short t[8]; uint4 u; } pk;
#pragma unroll
            for (int j = 0; j < 8; ++j) pk.t[j] = f2bf(T[od][ob + v8 * 8 + j]);
            *(uint4*)&vt[orow + s] = pk.u;
        }
    }
}

// ---------------------------------------------------------------------------
// Flash attention pass 1 (split-K): 32x32x16 MFMA, transposed-score.
// Block = 256 thr (4 waves), BQ=128 (32 q/wave), shared 32KB K/V staging.
// Grid: (25 q-tiles x NSPLIT, HEADS). Each block covers key chunks
// [split*nch/4, (split+1)*nch/4) and writes l-normalized partial O (bf16)
// plus m,l (fp32) for the combine pass.
// ---------------------------------------------------------------------------
__global__ __launch_bounds__(256, 3) void attn_part_kernel(
    const unsigned short* __restrict__ qb, const unsigned short* __restrict__ kb,
    const unsigned short* __restrict__ vt, unsigned short* __restrict__ part_o,
    float* __restrict__ part_ml)
{
    __shared__ short KV[16384]; // 32KB: Ks = KV (64x128), Vs = KV+8192 (128x64)
    short* Ks = KV;
    short* Vs = KV + 8192;

    const int tid = threadIdx.x;
    const int wv = tid >> 6;
    const int l  = tid & 63;
    const int h  = blockIdx.y;
    const int tile  = blockIdx.x >> 2;
    const int split = blockIdx.x & 3;
    const int q0 = tile * BQ;
    const int lhi = l >> 5;
    const int llo = l & 31;

    // ---- stage Q tile (128 rows x 128 d) into whole KV, pull B-frags ----
#pragma unroll
    for (int s = 0; s < 8; ++s) {
        const int shot = wv * 8 + s;
        const int row = shot * 4 + (l >> 4);
        const int gr = min(q0 + row, SEQ_LEN - 1);
        async16(KV + shot * 512, qb + (size_t)gr * DIM + h * HEAD_DIM + (l & 15) * 8);
    }
    __syncthreads();
    short8 qf[8];
#pragma unroll
    for (int ds = 0; ds < 8; ++ds)
        qf[ds] = *(const short8*)&KV[(wv * 32 + llo) * 128 + ds * 16 + lhi * 8];
    __syncthreads();

    const int myq = q0 + wv * 32 + llo;
    const int mylimit = (myq < FRAME_LEN) ? FRAME_LEN : SEQ_LEN;
    const int wave_lim = (q0 + wv * 32 < FRAME_LEN) ? FRAME_LEN : SEQ_LEN;
    const int Lmax = (q0 + BQ - 1 >= FRAME_LEN) ? SEQ_LEN : FRAME_LEN;
    const int nch = (Lmax + 63) >> 6;
    const int kc0 = ((split * nch) >> 2) * 64;
    const int kc1 = (((split + 1) * nch) >> 2) * 64;

    float m_run = -3.0e38f, l_run = 0.f;
    f32x16 o[4];
#pragma unroll
    for (int mt = 0; mt < 4; ++mt)
#pragma unroll
        for (int r = 0; r < 16; ++r) o[mt][r] = 0.f;

    // per-lane staging descriptors (loop-invariant). 4 shots each for K and V.
    int krloc[4], kcol[4], vcol[4];
    size_t vrow[4];
#pragma unroll
    for (int s = 0; s < 4; ++s) {
        krloc[s] = (wv * 4 + s) * 4 + (l >> 4);                 // local k-row 0..63
        kcol[s] = h * HEAD_DIM + (((l & 15) ^ (krloc[s] & 7)) * 8);
        const int d = (wv * 4 + s) * 8 + (l >> 3);              // d-row 0..127
        vrow[s] = (size_t)(h * HEAD_DIM + d) * SEQ_LEN;
        vcol[s] = ((l & 7) ^ (d & 7)) * 8;
    }

    for (int kc = kc0; kc < kc1; kc += 64) {
        // ---- stage K (xor-swizzled [krow][g^(krow&7)]) ----
#pragma unroll
        for (int s = 0; s < 4; ++s) {
            const int gr = min(kc + krloc[s], SEQ_LEN - 1);
            async16(Ks + (wv * 4 + s) * 512, kb + (size_t)gr * DIM + kcol[s]);
        }
        // ---- stage V^T (xor-swizzled [d][kg^(d&7)]) ----
#pragma unroll
        for (int s = 0; s < 4; ++s) {
            const int col = min(kc + vcol[s], SEQ_LEN - 8);
            async16(Vs + (wv * 4 + s) * 512, vt + vrow[s] + col);
        }
        __syncthreads();

        // ---- S^T = K Q^T : two 32x32 tiles per wave ----
        f32x16 st[2];
#pragma unroll
        for (int r = 0; r < 16; ++r) { st[0][r] = 0.f; st[1][r] = 0.f; }
#pragma unroll
        for (int ds = 0; ds < 8; ++ds) {
            const int gd = ds * 2 + lhi;
#pragma unroll
            for (int kt = 0; kt < 2; ++kt) {
                const int krow = kt * 32 + llo;
                short8 kf = *(const short8*)&Ks[krow * 128 + ((gd ^ (krow & 7)) * 8)];
                st[kt] = __builtin_amdgcn_mfma_f32_32x32x16_bf16(kf, qf[ds], st[kt], 0, 0, 0);
            }
        }

        // ---- block-causal / tail mask ----
        if (kc + 64 > wave_lim) {
#pragma unroll
            for (int kt = 0; kt < 2; ++kt)
#pragma unroll
                for (int r = 0; r < 16; ++r) {
                    const int kg = kc + kt * 32 + (r & 3) + 8 * (r >> 2) + 4 * lhi;
                    if (kg >= mylimit) st[kt][r] = -3.0e38f;
                }
        }

        // ---- online softmax; dead-chunk guard for fully-masked splits ----
        float vmax = st[0][0];
#pragma unroll
        for (int r = 1; r < 16; ++r) vmax = fmaxf(vmax, st[0][r]);
#pragma unroll
        for (int r = 0; r < 16; ++r) vmax = fmaxf(vmax, st[1][r]);
        vmax = fmaxf(vmax, __shfl_xor(vmax, 32));
        const float mn = fmaxf(m_run, vmax);
        const float mnc = (mn < -1.0e37f) ? 0.f : mn; // dead: exp(x-0)=0 for x=-3e38
        const float alpha = __expf(m_run - mnc);
        m_run = mn;
        float rs = 0.f;
        unsigned p16[2][8];
#pragma unroll
        for (int kt = 0; kt < 2; ++kt)
#pragma unroll
            for (int r2 = 0; r2 < 8; ++r2) {
                const float p0 = __expf(st[kt][2 * r2] - mnc);
                const float p1 = __expf(st[kt][2 * r2 + 1] - mnc);
                rs += p0 + p1;
                p16[kt][r2] = (unsigned)f2bf(p0) | ((unsigned)f2bf(p1) << 16);
            }
        rs += __shfl_xor(rs, 32);
        l_run = l_run * alpha + rs;
#pragma unroll
        for (int mt = 0; mt < 4; ++mt)
#pragma unroll
            for (int r = 0; r < 16; ++r) o[mt][r] *= alpha;

        // ---- O^T += V^T P^T : P^T B-frags via half-wave exchange ----
#pragma unroll
        for (int kblk = 0; kblk < 4; ++kblk) {
            const int t = kblk >> 1;
            const int dk    = ((kblk & 1) * 2 + lhi) * 2;
            const int dsend = ((kblk & 1) * 2 + (1 - lhi)) * 2;
            const unsigned r0 = __shfl_xor(p16[t][dsend], 32);
            const unsigned r1 = __shfl_xor(p16[t][dsend + 1], 32);
            union { unsigned u[4]; short8 s8; } pf;
            if (lhi == 0) { pf.u[0] = p16[t][dk]; pf.u[1] = p16[t][dk + 1]; pf.u[2] = r0; pf.u[3] = r1; }
            else          { pf.u[0] = r0; pf.u[1] = r1; pf.u[2] = p16[t][dk]; pf.u[3] = p16[t][dk + 1]; }
#pragma unroll
            for (int mt = 0; mt < 4; ++mt) {
                const int vd = mt * 32 + llo;
                short8 vf = *(const short8*)&Vs[vd * 64 + (((kblk * 2 + lhi) ^ (vd & 7)) * 8)];
                o[mt] = __builtin_amdgcn_mfma_f32_32x32x16_bf16(vf, pf.s8, o[mt], 0, 0, 0);
            }
        }
        __syncthreads();
    }

    // ---- epilogue: store l-normalized partial O (bf16) + m,l (fp32) ----
    const int slot = (tile * NSPLIT + split) * HEADS + h;
    const int qloc = wv * 32 + llo;
    const float inv = (l_run > 0.f) ? 1.0f / l_run : 0.f;
    unsigned short* op = part_o + (size_t)slot * (BQ * HEAD_DIM) + qloc * HEAD_DIM + 4 * lhi;
#pragma unroll
    for (int mt = 0; mt < 4; ++mt)
#pragma unroll
        for (int g = 0; g < 4; ++g) {
            union { unsigned short t4[4]; uint2 u; } pk;
#pragma unroll
            for (int i = 0; i < 4; ++i) pk.t4[i] = f2bf(o[mt][4 * g + i] * inv);
            *(uint2*)&op[mt * 32 + 8 * g] = pk.u;
        }
    if (lhi == 0) {
        part_ml[(size_t)slot * 256 + qloc] = m_run;
        part_ml[(size_t)slot * 256 + 128 + qloc] = l_run;
    }
}

// ---------------------------------------------------------------------------
// Combine pass: merge NSPLIT partials per (q, head) -> attb bf16.
// Grid (3120/8, HEADS), block 256: thread -> (row r=tid>>5, 4 d-cols).
// ---------------------------------------------------------------------------
__global__ __launch_bounds__(256) void attn_combine_kernel(
    const unsigned short* __restrict__ part_o, const float* __restrict__ part_ml,
    unsigned short* __restrict__ attb)
{
    const int h = blockIdx.y;
    const int q = blockIdx.x * 8 + (threadIdx.x >> 5);
    const int dq = (threadIdx.x & 31) * 4;
    const int tile = q >> 7, qloc = q & 127;

    float ms[NSPLIT], ls[NSPLIT];
    float m = -3.0e38f;
#pragma unroll
    for (int s = 0; s < NSPLIT; ++s) {
        const size_t base = (size_t)((tile * NSPLIT + s) * HEADS + h) * 256;
        ms[s] = part_ml[base + qloc];
        ls[s] = part_ml[base + 128 + qloc];
        m = fmaxf(m, ms[s]);
    }
    float W = 0.f;
    float acc[4] = {0.f, 0.f, 0.f, 0.f};
#pragma unroll
    for (int s = 0; s < NSPLIT; ++s) {
        const float w = __expf(ms[s] - m) * ls[s];
        W += w;
        const unsigned short* po = part_o +
            (size_t)((tile * NSPLIT + s) * HEADS + h) * (BQ * HEAD_DIM) + qloc * HEAD_DIM + dq;
        uint2 u = *(const uint2*)po;
        acc[0] += w * bf2f((unsigned short)(u.x & 0xffff));
        acc[1] += w * bf2f((unsigned short)(u.x >> 16));
        acc[2] += w * bf2f((unsigned short)(u.y & 0xffff));
        acc[3] += w * bf2f((unsigned short)(u.y >> 16));
    }
    const float inv = 1.0f / W;
    union { unsigned short t4[4]; uint2 u; } pk;
#pragma unroll
    for (int i = 0; i < 4; ++i) pk.t4[i] = f2bf(acc[i] * inv);
    *(uint2*)&attb[(size_t)q * DIM + h * HEAD_DIM + dq] = pk.u;
}

// ---------------------------------------------------------------------------
extern "C" void kernel_launch(void* const* d_in, const int* in_sizes, int n_in,
                              void* d_out, int out_size, void* d_ws, size_t ws_size,
                              hipStream_t stream)
{
    const float* hs    = (const float*)d_in[0];
    const float* cosf  = (const float*)d_in[1];
    const float* sinf  = (const float*)d_in[2];
    const float* w_qkv = (const float*)d_in[3];
    const float* b_qkv = (const float*)d_in[4];
    const float* g_q   = (const float*)d_in[5];
    const float* g_k   = (const float*)d_in[6];
    const float* w_out = (const float*)d_in[7];
    const float* b_out = (const float*)d_in[8];

    // workspace layout, 105,136,128 B total (same footprint as round 3).
    // partials live in the qkv fp32 region (dead after vtrans).
    char* base = (char*)d_ws;
    unsigned short* qb    = (unsigned short*)base;                 //  9,584,640
    unsigned short* kb    = (unsigned short*)(base + 9584640);     //  9,584,640
    unsigned short* vt    = (unsigned short*)(base + 19169280);    //  9,584,640 (alias hsb)
    unsigned short* hsb   = vt;
    float*          qkv   = (float*)(base + 28753920);             // 57,507,840
    unsigned short* part_o = (unsigned short*)(base + 28753920);   // 39,321,600 (alias qkv)
    float*          part_ml = (float*)(base + 68075520);           //  1,228,800 (alias qkv)
    unsigned short* wqkvT = (unsigned short*)(base + 86261760);    // 14,155,776 (alias attb)
    unsigned short* attb  = wqkvT;
    unsigned short* woutT = (unsigned short*)(base + 100417536);   //  4,718,592
    float* outp = (float*)d_out;

    // 1) hs -> bf16
    convert_bf16_kernel<<<2340, 256, 0, stream>>>(hs, hsb);
    // 2) w_qkv -> bf16 transposed [4608][1536]
    transpose_bf16_kernel<<<dim3(QKV_N / 64, DIM / 64), 256, 0, stream>>>(w_qkv, wqkvT, DIM, QKV_N);
    // 3) w_out -> bf16 transposed [1536][1536]
    transpose_bf16_kernel<<<dim3(DIM / 64, DIM / 64), 256, 0, stream>>>(w_out, woutT, DIM, DIM);
    // 4) qkv = hs @ w_qkv + b_qkv (fp32 out)
    gemm_bt_kernel<<<dim3(QKV_N / 128, (SEQ_LEN + 127) / 128), 256, 0, stream>>>(
        hsb, wqkvT, b_qkv, qkv, SEQ_LEN, QKV_N, DIM);
    // 5) rmsnorm+rope -> qb, kb (q pre-scaled by 1/sqrt(hd))
    rmsrope_kernel<<<SEQ_LEN, 256, 0, stream>>>(qkv, g_q, g_k, cosf, sinf, qb, kb);
    // 6) v -> vt bf16 [h][d][s]
    vtrans_kernel<<<dim3((SEQ_LEN + 63) / 64, HEADS), 256, 0, stream>>>(qkv, vt);
    // 7a) attention pass 1: partials per (tile, split, head)
    attn_part_kernel<<<dim3(((SEQ_LEN + BQ - 1) / BQ) * NSPLIT, HEADS), 256, 0, stream>>>(
        qb, kb, vt, part_o, part_ml);
    // 7b) combine -> attb bf16 [s][h*128+d]
    attn_combine_kernel<<<dim3(SEQ_LEN / 8, HEADS), 256, 0, stream>>>(part_o, part_ml, attb);
    // 8) out = attb @ w_out + b_out (fp32)
    gemm_bt_kernel<<<dim3(DIM / 128, (SEQ_LEN + 127) / 128), 256, 0, stream>>>(
        attb, woutT, b_out, outp, SEQ_LEN, DIM, DIM);
}